// Round 8
// baseline (284.567 us; speedup 1.0000x reference)
//
#include <hip/hip_runtime.h>

typedef short short8 __attribute__((ext_vector_type(8)));
typedef short short4v __attribute__((ext_vector_type(4)));
typedef float f32x4 __attribute__((ext_vector_type(4)));

#define B_ROWS 32768
#define DIN 784
#define D_DIM 256
#define T_TILES 16
#define C_DIM 64
#define BM 64
#define NT 512
#define NCHUNK 25   // ceil(784/32)

// ---- ws layout (bytes) ----
#define WPT_OFF 0u        // bf16 frag [25 chunks][16 g][64 lane][8] = 409600 B
#define WCT_OFF 409600u   // bf16 frag [16 t][8 ks][4 cf][64 lane][8] = 524288 B
#define WS_OFF  933888u   // f64 [16 t][800 k] = 102400 B (k 784..799 zeroed)
#define BS_OFF  1036288u  // f64 [16]

static __device__ inline unsigned short f2bf(float f) {
    unsigned u = __builtin_bit_cast(unsigned, f);
    u += 0x7fffu + ((u >> 16) & 1u);          // RNE
    return (unsigned short)(u >> 16);
}
static __device__ inline double qtern(float s) {
    double v = (double)s;
    return (v > 0.3) ? 1.0 : ((v < -0.3) ? -1.0 : 0.0);
}

// ========== prep: wpt frag (bf16), wct frag (bf16), Ws t-major f64, bs ======
__global__ __launch_bounds__(256)
void prep_kernel(const float* __restrict__ Wp, const float* __restrict__ bp,
                 const float* __restrict__ sigs_raw, const float* __restrict__ Wc,
                 char* __restrict__ ws) {
    __shared__ __align__(16) char u2[34816];
    const int bid = blockIdx.x, tid = threadIdx.x;
    unsigned short* wpt = (unsigned short*)(ws + WPT_OFF);
    unsigned short* wct = (unsigned short*)(ws + WCT_OFF);
    double* Ws2 = (double*)(ws + WS_OFF);
    double* bsd = (double*)(ws + BS_OFF);

    if (bid < 25) {
        // transpose Wp[k0..k0+32)[256] -> lt[col][k&31], then frag layout out
        unsigned short (*lt)[40] = (unsigned short (*)[40])u2;    // [256][40]
        const int k0 = bid * 32;
        #pragma unroll
        for (int p = 0; p < 8; ++p) {
            const int k = p * 4 + (tid >> 6);
            const int c = (tid & 63) * 4;
            float4 v = make_float4(0.f, 0.f, 0.f, 0.f);
            if (k0 + k < DIN) v = *(const float4*)&Wp[(size_t)(k0 + k) * D_DIM + c];
            lt[c + 0][k] = f2bf(v.x); lt[c + 1][k] = f2bf(v.y);
            lt[c + 2][k] = f2bf(v.z); lt[c + 3][k] = f2bf(v.w);
        }
        __syncthreads();
        // frag: dst short8 index f = g*64 + l ; col = g*16+(l&15), k8 = (l>>4)*8
        #pragma unroll
        for (int i = 0; i < 4; ++i) {
            const int f = i * 256 + tid;            // 0..1023
            const int g = f >> 6, l = f & 63;
            const short8 v = *(const short8*)&lt[g * 16 + (l & 15)][(l >> 4) * 8];
            *(short8*)(wpt + (size_t)bid * 8192 + f * 8) = v;
        }
    } else if (bid < 123) {
        // Ws2[t][k0..k0+8) f64
        float* sigq = (float*)u2;               // [16][256]
        float* wp8  = (float*)(u2 + 16384);     // [8][256]
        const int k0 = (bid - 25) * 8;
        #pragma unroll
        for (int i = 0; i < 16; ++i) {
            const int idx = i * 256 + tid;
            sigq[idx] = (float)qtern(sigs_raw[idx]);
        }
        #pragma unroll
        for (int i = 0; i < 8; ++i)
            wp8[i * 256 + tid] = Wp[(size_t)(k0 + i) * D_DIM + tid];
        __syncthreads();
        const int kk = tid >> 5, t = (tid >> 1) & 15, half = tid & 1;
        double s = 0.0;
        const float* wr = &wp8[kk * 256 + half * 128];
        const float* sq = &sigq[t * 256 + half * 128];
        for (int d = 0; d < 128; ++d) s += (double)wr[d] * (double)sq[d];
        s += __shfl_xor(s, 1);
        if (half == 0) Ws2[(size_t)t * 800 + k0 + kk] = s;
    } else if (bid < 139) {
        // WcT tile t -> lc[col][k] -> frag layout
        unsigned short (*lc)[264] = (unsigned short (*)[264])u2;  // [64][264]
        const int t = bid - 123;
        #pragma unroll
        for (int j = 0; j < 16; ++j) {
            const int f4 = j * 256 + tid;
            const int d  = f4 >> 4;
            const int c4 = (f4 & 15) * 4;
            const float4 v = *(const float4*)&Wc[((size_t)t * D_DIM + d) * C_DIM + c4];
            lc[c4 + 0][d] = f2bf(v.x); lc[c4 + 1][d] = f2bf(v.y);
            lc[c4 + 2][d] = f2bf(v.z); lc[c4 + 3][d] = f2bf(v.w);
        }
        __syncthreads();
        // frag: f = ((ks*4+cf)*64+l) ; col = cf*16+(l&15) ; k = ks*32+(l>>4)*8
        #pragma unroll
        for (int i = 0; i < 8; ++i) {
            const int f = i * 256 + tid;            // 0..2047
            const int l = f & 63, cfks = f >> 6;
            const int cf = cfks & 3, ks = cfks >> 2;
            const short8 v = *(const short8*)&lc[cf * 16 + (l & 15)][ks * 32 + (l >> 4) * 8];
            *(short8*)(wct + (size_t)t * 16384 + f * 8) = v;
        }
    } else {
        // bs[t] = bp @ sig_t ; zero Ws2 pad k=784..799
        Ws2[(size_t)(tid >> 4) * 800 + 784 + (tid & 15)] = 0.0;
        const int t = tid >> 4, l = tid & 15;
        double s = 0.0;
        #pragma unroll
        for (int j = 0; j < 16; ++j) {
            const int d = l * 16 + j;
            s += (double)bp[d] * qtern(sigs_raw[t * D_DIM + d]);
        }
        #pragma unroll
        for (int m = 8; m >= 1; m >>= 1) s += __shfl_xor(s, m);
        if (l == 0) bsd[t] = s;
    }
}

// ========== fused: h(MFMA) + scores(f64, scalar Ws) + argmax + logits =======
__global__ __launch_bounds__(NT, 4)
void fused_kernel(const float* __restrict__ x, const float* __restrict__ bp,
                  const float* __restrict__ bc, const char* __restrict__ ws,
                  float* __restrict__ out) {
    __shared__ __align__(16) char u[33792];           // xls+Abuf, later h_s[64][264]
    __shared__ __align__(16) double score_s[64 * 17]; // 8704 B
    __shared__ int tidx_s[BM];
    __shared__ int counts_s[16], starts_s[17];
    __shared__ int rows_local[BM];
    __shared__ int sub_t[24], sub_s[24], sub_c[24], nsubs_s;

    float*          xls  = (float*)u;                     // [2][64*33] f32
    unsigned short* Abuf = (unsigned short*)(u + 16896);  // [2][64*40] bf16

    const unsigned short* wpt = (const unsigned short*)(ws + WPT_OFF);
    const unsigned short* wct = (const unsigned short*)(ws + WCT_OFF);
    const double* Wsg = (const double*)(ws + WS_OFF);
    const double* bsd = (const double*)(ws + BS_OFF);

    const int tid  = threadIdx.x;
    const int row0 = blockIdx.x * BM;
    const int wid  = tid >> 6, lane = tid & 63;
    const int wr   = wid >> 2, wcid = wid & 3;     // 2 row-halves x 4 col-quarters
    const int lrow = lane & 15, kgo = (lane >> 4) * 8;
    const int ar   = tid >> 3, ako = (tid & 7) * 4;  // staging: row, 4-float k-offset

    const int wid_u = __builtin_amdgcn_readfirstlane(wid);
    const double* W0 = Wsg + (size_t)(2 * wid_u) * 800;   // uniform -> s_load path
    const double* W1 = W0 + 800;

    f32x4 acc[2][4];
    #pragma unroll
    for (int i = 0; i < 2; ++i)
        #pragma unroll
        for (int j = 0; j < 4; ++j) acc[i][j] = (f32x4){0.f, 0.f, 0.f, 0.f};
    double s0a = 0.0, s0b = 0.0, s1a = 0.0, s1b = 0.0;

    // ---- prologue: stage chunk 0 (x f32 -> xls[0], bf16 -> Abuf[0]) ----
    {
        const float4 v = *(const float4*)&x[(size_t)(row0 + ar) * DIN + ako];
        *(float4*)(xls + ar * 33 + ako) = v;
        unsigned short t4[4] = {f2bf(v.x), f2bf(v.y), f2bf(v.z), f2bf(v.w)};
        *(short4v*)(Abuf + ar * 40 + ako) = *(short4v*)t4;
    }
    __syncthreads();

    for (int c = 0; c < NCHUNK; ++c) {
        const int cur = c & 1;
        const bool more = (c + 1 < NCHUNK);
        float4 vnx = make_float4(0.f, 0.f, 0.f, 0.f);
        if (more) {
            const int kb = (c + 1) * 32 + ako;
            if (kb < DIN) vnx = *(const float4*)&x[(size_t)(row0 + ar) * DIN + kb];
        }

        // ---- MFMA: A from Abuf[cur], B frags coalesced from L2 wpt ----
        {
            const unsigned short* Ab = Abuf + cur * 2560;
            const short8 af0 = *(const short8*)(Ab + (wr * 32 + lrow) * 40 + kgo);
            const short8 af1 = *(const short8*)(Ab + (wr * 32 + 16 + lrow) * 40 + kgo);
            #pragma unroll
            for (int cf = 0; cf < 4; ++cf) {
                const int g = wcid * 4 + cf;
                const short8 bfr = *(const short8*)(wpt + ((size_t)c * 16 + g) * 512 + lane * 8);
                acc[0][cf] = __builtin_amdgcn_mfma_f32_16x16x32_bf16(af0, bfr, acc[0][cf], 0, 0, 0);
                acc[1][cf] = __builtin_amdgcn_mfma_f32_16x16x32_bf16(af1, bfr, acc[1][cf], 0, 0, 0);
            }
        }

        // ---- f64 scores: lane=row, wave's 2 tiles, Ws via scalar loads ----
        {
            const float*  xr  = xls + cur * 2112 + lane * 33;
            const double* W0c = W0 + c * 32;
            const double* W1c = W1 + c * 32;
            #pragma unroll
            for (int j = 0; j < 8; ++j) {
                const f32x4 xv = *(const f32x4*)(xr + j * 4);
                const double x0 = (double)xv[0], x1 = (double)xv[1];
                const double x2 = (double)xv[2], x3 = (double)xv[3];
                s0a += x0 * W0c[j * 4 + 0]; s0b += x1 * W0c[j * 4 + 1];
                s0a += x2 * W0c[j * 4 + 2]; s0b += x3 * W0c[j * 4 + 3];
                s1a += x0 * W1c[j * 4 + 0]; s1b += x1 * W1c[j * 4 + 1];
                s1a += x2 * W1c[j * 4 + 2]; s1b += x3 * W1c[j * 4 + 3];
            }
        }

        // ---- stage chunk c+1 ----
        if (more) {
            *(float4*)(xls + (cur ^ 1) * 2112 + ar * 33 + ako) = vnx;
            unsigned short t4[4] = {f2bf(vnx.x), f2bf(vnx.y), f2bf(vnx.z), f2bf(vnx.w)};
            *(short4v*)(Abuf + (cur ^ 1) * 2560 + ar * 40 + ako) = *(short4v*)t4;
        }
        __syncthreads();
    }

    // ---- h epilogue -> h_s LDS (bf16), overlays staging buffers ----
    unsigned short* h_s = (unsigned short*)u;    // [64][264]
    #pragma unroll
    for (int cf = 0; cf < 4; ++cf) {
        const int gc = wcid * 64 + cf * 16 + lrow;
        const float bpv = bp[gc];
        #pragma unroll
        for (int rf = 0; rf < 2; ++rf) {
            const int lr = wr * 32 + rf * 16 + (lane >> 4) * 4;
            #pragma unroll
            for (int r = 0; r < 4; ++r)
                h_s[(lr + r) * 264 + gc] = f2bf(acc[rf][cf][r] + bpv);
        }
    }
    // scores -> LDS
    score_s[lane * 17 + 2 * wid]     = s0a + s0b + bsd[2 * wid];
    score_s[lane * 17 + 2 * wid + 1] = s1a + s1b + bsd[2 * wid + 1];
    __syncthreads();

    // ---- argmax per row ----
    if (tid < BM) {
        const double* s = &score_s[tid * 17];
        double best = s[0]; int bi = 0;
        #pragma unroll
        for (int t = 1; t < 16; ++t)
            if (s[t] > best) { best = s[t]; bi = t; }
        tidx_s[tid] = bi;
        out[(size_t)B_ROWS * C_DIM + row0 + tid] = (float)bi;
    }
    __syncthreads();

    // ---- block-local bucketing ----
    if (tid < 16) {
        int c = 0;
        for (int r = 0; r < BM; ++r) c += (tidx_s[r] == tid);
        counts_s[tid] = c;
    }
    __syncthreads();
    if (tid == 0) {
        int a = 0, n = 0;
        for (int t = 0; t < 16; ++t) {
            starts_s[t] = a;
            int cc = counts_s[t], s = a;
            a += cc;
            while (cc > 0) { sub_t[n] = t; sub_s[n] = s; sub_c[n] = (cc < 16 ? cc : 16); s += 16; cc -= 16; ++n; }
        }
        starts_s[16] = a;
        nsubs_s = n;
    }
    __syncthreads();
    if (tid < 16) {
        int pos = starts_s[tid];
        for (int r = 0; r < BM; ++r)
            if (tidx_s[r] == tid) rows_local[pos++] = r;
    }
    __syncthreads();

    // ---- logits: waves take 16-row sub-tiles, barrier-free ----
    const int ns = nsubs_s;
    for (int si = wid; si < ns; si += 8) {
        const int t = sub_t[si], sbase = sub_s[si], cnt = sub_c[si];
        const int arow = rows_local[sbase + (lrow < cnt ? lrow : cnt - 1)];
        f32x4 a2[4];
        #pragma unroll
        for (int i = 0; i < 4; ++i) a2[i] = (f32x4){0.f, 0.f, 0.f, 0.f};
        #pragma unroll
        for (int ks = 0; ks < 8; ++ks) {
            const short8 af = *(const short8*)(h_s + arow * 264 + ks * 32 + kgo);
            #pragma unroll
            for (int cf = 0; cf < 4; ++cf) {
                const short8 bf = *(const short8*)(wct + (size_t)t * 16384 + ((ks * 4 + cf) * 64 + lane) * 8);
                a2[cf] = __builtin_amdgcn_mfma_f32_16x16x32_bf16(af, bf, a2[cf], 0, 0, 0);
            }
        }
        #pragma unroll
        for (int cf = 0; cf < 4; ++cf) {
            const int col = cf * 16 + lrow;
            const float bcv = bc[t * C_DIM + col];
            #pragma unroll
            for (int r = 0; r < 4; ++r) {
                const int j = (lane >> 4) * 4 + r;
                if (j < cnt)
                    out[(size_t)(row0 + rows_local[sbase + j]) * C_DIM + col] = a2[cf][r] + bcv;
            }
        }
    }
}

extern "C" void kernel_launch(void* const* d_in, const int* in_sizes, int n_in,
                              void* d_out, int out_size, void* d_ws, size_t ws_size,
                              hipStream_t stream) {
    const float* x    = (const float*)d_in[0];
    const float* Wp   = (const float*)d_in[1];
    const float* bp   = (const float*)d_in[2];
    const float* sigs = (const float*)d_in[3];
    const float* Wc   = (const float*)d_in[4];
    const float* bc   = (const float*)d_in[5];
    float* out = (float*)d_out;
    char* ws = (char*)d_ws;

    prep_kernel<<<dim3(140), dim3(256), 0, stream>>>(Wp, bp, sigs, Wc, ws);
    fused_kernel<<<dim3(B_ROWS / BM), dim3(NT), 0, stream>>>(x, bp, bc, ws, out);
}